// Round 1
// baseline (545.985 us; speedup 1.0000x reference)
//
#include <hip/hip_runtime.h>
#include <hip/hip_bf16.h>

// Problem constants (Head_24799141167224)
// Inputs fp32, output fp32 (compared at bf16 precision, 2% rel).
// ws cap: 10,137,856 B proven (R4 fault at 11.2 MB). d_out = scratch until attn.
#define NB 4
#define NT 4096
#define NC 2048
#define ND 128
#define NK 409      // int(0.1 * 4096)
#define KPAD 416
#define NM (NB * NK)   // 1636

typedef __attribute__((ext_vector_type(8))) short short8;   // 8 bf16
typedef __attribute__((ext_vector_type(4))) float f32x4;

union S8U { short8 v; ushort u[8]; };

// RNE split: x = hi + lo (both bf16), |x - hi - lo| <= ~2^-18 |x|
__device__ __forceinline__ void split2(float x, ushort& h, ushort& l) {
    union { float f; unsigned u; } a; a.f = x;
    unsigned r = a.u + 0x7FFFu + ((a.u >> 16) & 1u);
    h = (ushort)(r >> 16);
    union { unsigned u; float f; } hb; hb.u = ((unsigned)h) << 16;
    float res = x - hb.f;
    union { float f; unsigned u; } b; b.f = res;
    unsigned r2 = b.u + 0x7FFFu + ((b.u >> 16) & 1u);
    l = (ushort)(r2 >> 16);
}

__device__ __forceinline__ uint4 pack8(const ushort* s) {
    uint4 v;
    v.x = (unsigned)s[0] | ((unsigned)s[1] << 16);
    v.y = (unsigned)s[2] | ((unsigned)s[3] << 16);
    v.z = (unsigned)s[4] | ((unsigned)s[5] << 16);
    v.w = (unsigned)s[6] | ((unsigned)s[7] << 16);
    return v;
}

// B tile-major slot with bank swizzle: 16 consecutive n at fixed lq spread
// over all 8 bank-groups (2-way aliasing = free, m136).
__device__ __forceinline__ int slotOf(int n, int lq) {
    return n * 4 + ((lq + (n >> 1)) & 3);
}

// async global->LDS, 16 B per lane; lds base wave-uniform, HW adds lane*16
__device__ __forceinline__ void gll16(const void* g, void* l) {
    __builtin_amdgcn_global_load_lds(
        (const __attribute__((address_space(1))) unsigned*)g,
        (__attribute__((address_space(3))) unsigned*)l, 16, 0, 0);
}

// ---------------------------------------------------------------------------
// Kernel 0: W [2048][128] fp32 -> Bt tile-major bf16 hi/lo:
// Bt[kt][part][slot][8 ushorts], kt=k/32, slot=slotOf(n,lq), elems k=lq*8+j.
// 1 MB per weight matrix. One block per kt.
// ---------------------------------------------------------------------------
__global__ __launch_bounds__(256) void bconv_tiles(
    const float* __restrict__ W, ushort* __restrict__ Bt)
{
    const int kt = blockIdx.x;       // 0..63
    const int t = threadIdx.x;
    const int n = t & 127;
    const int lq0 = (t >> 7) * 2;    // 0 or 2
    #pragma unroll
    for (int e = 0; e < 2; ++e) {
        int lq = lq0 + e;
        ushort h[8], l[8];
        #pragma unroll
        for (int j = 0; j < 8; ++j) {
            float x = W[(size_t)(kt * 32 + lq * 8 + j) * ND + n];  // coalesced
            split2(x, h[j], l[j]);
        }
        int slot = slotOf(n, lq);
        *(uint4*)&Bt[((size_t)(kt * 2 + 0) * 512 + slot) * 8] = pack8(h);
        *(uint4*)&Bt[((size_t)(kt * 2 + 1) * 512 + slot) * 8] = pack8(l);
    }
}

// ---------------------------------------------------------------------------
// Kernel 1: q = index @ Wq. 128x128 tile, waves 2x2 (64x64 each, mi=4).
// R9: split-K=8 (grid (128,8) = 1024 blocks = 4 blocks/CU; was 2 -> 1 blk/CU,
// Occupancy 10% and ~90% latency stall). Accumulate via atomicAdd into a
// zeroed q (8 partial buffers don't fit ws). gridDim.x=128 % 8 == 0 so all
// K-splits of an m-tile share an XCD under linear round-robin dispatch ->
// same-L2 atomics. __launch_bounds__(256,4) keeps VGPR<=128 for 4 waves/SIMD.
// ---------------------------------------------------------------------------
#define QSPLIT 8
__global__ __launch_bounds__(256, 4) void qgemm_v3(
    const float* __restrict__ A, const ushort* __restrict__ Bt,
    float* __restrict__ q)
{
    __shared__ __align__(16) ushort BS[2][2][4096];   // [buf][hi/lo][slot*8] 32 KB

    const int tid = threadIdx.x;
    const int w = tid >> 6, lane = tid & 63;
    const int wm = w >> 1, wn = w & 1;
    const int lrow = lane & 15, lq = lane >> 4;
    const int m0 = blockIdx.x * 128;
    const int kb = blockIdx.y * (NC / QSPLIT);            // *256
    const int kt0 = blockIdx.y * ((NC / QSPLIT) / 32);    // *8
    const int KITER = (NC / QSPLIT) / 32;                 // 8

    const float* arow[4];
    #pragma unroll
    for (int mi = 0; mi < 4; ++mi)
        arow[mi] = A + (size_t)(m0 + wm * 64 + mi * 16 + lrow) * NC + kb + lq * 8;

    int boff[4];
    #pragma unroll
    for (int ni = 0; ni < 4; ++ni)
        boff[ni] = slotOf(wn * 64 + ni * 16 + lrow, lq) * 8;

    f32x4 acc[4][4];
    #pragma unroll
    for (int i = 0; i < 4; ++i)
        #pragma unroll
        for (int j = 0; j < 4; ++j) acc[i][j] = (f32x4){0.f, 0.f, 0.f, 0.f};

    // prologue: stage tile 0 (B) + load tile 0 (A)
    {
        const ushort* gt = Bt + (size_t)kt0 * 2 * 512 * 8;
        #pragma unroll
        for (int p = 0; p < 2; ++p)
            #pragma unroll
            for (int c2 = 0; c2 < 2; ++c2) {
                int c = 2 * w + c2;   // wave-uniform
                gll16(gt + ((size_t)p * 512 + c * 64 + lane) * 8,
                      &BS[0][p][(c * 64) * 8]);
            }
    }
    float4 fa[8];
    #pragma unroll
    for (int mi = 0; mi < 4; ++mi) {
        fa[2 * mi + 0] = *(const float4*)(arow[mi] + 0);
        fa[2 * mi + 1] = *(const float4*)(arow[mi] + 4);
    }
    __syncthreads();

    for (int kt = 0; kt < KITER; ++kt) {
        const int buf = kt & 1;
        if (kt + 1 < KITER) {   // stage next B tile into other buffer
            const ushort* gt = Bt + (size_t)(kt0 + kt + 1) * 2 * 512 * 8;
            #pragma unroll
            for (int p = 0; p < 2; ++p)
                #pragma unroll
                for (int c2 = 0; c2 < 2; ++c2) {
                    int c = 2 * w + c2;
                    gll16(gt + ((size_t)p * 512 + c * 64 + lane) * 8,
                          &BS[buf ^ 1][p][(c * 64) * 8]);
                }
        }
        // split current A into bf16 hi/lo fragments (registers only)
        short8 ah[4], al[4];
        #pragma unroll
        for (int mi = 0; mi < 4; ++mi) {
            S8U H, L;
            float xs[8] = {fa[2*mi].x, fa[2*mi].y, fa[2*mi].z, fa[2*mi].w,
                           fa[2*mi+1].x, fa[2*mi+1].y, fa[2*mi+1].z, fa[2*mi+1].w};
            #pragma unroll
            for (int j = 0; j < 8; ++j) split2(xs[j], H.u[j], L.u[j]);
            ah[mi] = H.v; al[mi] = L.v;
        }
        if (kt + 1 < KITER) {   // prefetch next A tile
            #pragma unroll
            for (int mi = 0; mi < 4; ++mi) {
                fa[2 * mi + 0] = *(const float4*)(arow[mi] + (kt + 1) * 32);
                fa[2 * mi + 1] = *(const float4*)(arow[mi] + (kt + 1) * 32 + 4);
            }
        }
        #pragma unroll
        for (int ni = 0; ni < 4; ++ni) {
            short8 bh = *(const short8*)&BS[buf][0][boff[ni]];
            short8 bl = *(const short8*)&BS[buf][1][boff[ni]];
            #pragma unroll
            for (int mi = 0; mi < 4; ++mi) {
                acc[mi][ni] = __builtin_amdgcn_mfma_f32_16x16x32_bf16(ah[mi], bh, acc[mi][ni], 0, 0, 0);
                acc[mi][ni] = __builtin_amdgcn_mfma_f32_16x16x32_bf16(ah[mi], bl, acc[mi][ni], 0, 0, 0);
                acc[mi][ni] = __builtin_amdgcn_mfma_f32_16x16x32_bf16(al[mi], bh, acc[mi][ni], 0, 0, 0);
            }
        }
        __syncthreads();
    }

    // C/D layout: col = lane&15, row = lq*4 + r. Atomic split-K accumulate.
    #pragma unroll
    for (int ni = 0; ni < 4; ++ni) {
        const int col = wn * 64 + ni * 16 + lrow;
        #pragma unroll
        for (int mi = 0; mi < 4; ++mi)
            #pragma unroll
            for (int r = 0; r < 4; ++r) {
                const int grow = m0 + wm * 64 + mi * 16 + lq * 4 + r;
                atomicAdd(&q[(size_t)grow * ND + col], acc[mi][ni][r]);
            }
    }
}

// ---------------------------------------------------------------------------
// Kernel 1b: gathered K/V projection, same structure. M-tile 64 (waves 2x2 of
// 32x64, mi=2). R9: split-K=8 -> grid (26, 8, 2) = 416 blocks (was 104 =
// 0.4 blk/CU, 60% of CUs idle). Already atomic, so pure grid change.
// ---------------------------------------------------------------------------
#define KVSPLIT 8
__global__ __launch_bounds__(256, 4) void kvgemm_v3(
    const float* __restrict__ X, const ushort* __restrict__ Bkt,
    const ushort* __restrict__ Bvt, const int* __restrict__ topi,
    float* __restrict__ ktop, float* __restrict__ vtop)
{
    __shared__ __align__(16) ushort BS[2][2][4096];

    const int tid = threadIdx.x;
    const int w = tid >> 6, lane = tid & 63;
    const int wm = w >> 1, wn = w & 1;
    const int lrow = lane & 15, lq = lane >> 4;
    const int m0 = blockIdx.x * 64;
    const int kb = blockIdx.y * (NC / KVSPLIT);           // *256
    const int kt0 = blockIdx.y * ((NC / KVSPLIT) / 32);   // *8
    const ushort* __restrict__ Bt = blockIdx.z ? Bvt : Bkt;
    const int KITER = (NC / KVSPLIT) / 32;                // 8

    const float* arow[2];
    #pragma unroll
    for (int mi = 0; mi < 2; ++mi) {
        int gi = m0 + wm * 32 + mi * 16 + lrow;
        int giC = gi < NM ? gi : NM - 1;
        int b = giC / NK, ii = giC % NK;
        int src = topi[b * KPAD + ii];
        arow[mi] = X + ((size_t)b * NT + src) * NC + kb + lq * 8;
    }
    int boff[4];
    #pragma unroll
    for (int ni = 0; ni < 4; ++ni)
        boff[ni] = slotOf(wn * 64 + ni * 16 + lrow, lq) * 8;

    f32x4 acc[2][4];
    #pragma unroll
    for (int i = 0; i < 2; ++i)
        #pragma unroll
        for (int j = 0; j < 4; ++j) acc[i][j] = (f32x4){0.f, 0.f, 0.f, 0.f};

    {
        const ushort* gt = Bt + (size_t)kt0 * 2 * 512 * 8;
        #pragma unroll
        for (int p = 0; p < 2; ++p)
            #pragma unroll
            for (int c2 = 0; c2 < 2; ++c2) {
                int c = 2 * w + c2;
                gll16(gt + ((size_t)p * 512 + c * 64 + lane) * 8,
                      &BS[0][p][(c * 64) * 8]);
            }
    }
    float4 fa[4];
    #pragma unroll
    for (int mi = 0; mi < 2; ++mi) {
        fa[2 * mi + 0] = *(const float4*)(arow[mi] + 0);
        fa[2 * mi + 1] = *(const float4*)(arow[mi] + 4);
    }
    __syncthreads();

    for (int kt = 0; kt < KITER; ++kt) {
        const int buf = kt & 1;
        if (kt + 1 < KITER) {
            const ushort* gt = Bt + (size_t)(kt0 + kt + 1) * 2 * 512 * 8;
            #pragma unroll
            for (int p = 0; p < 2; ++p)
                #pragma unroll
                for (int c2 = 0; c2 < 2; ++c2) {
                    int c = 2 * w + c2;
                    gll16(gt + ((size_t)p * 512 + c * 64 + lane) * 8,
                          &BS[buf ^ 1][p][(c * 64) * 8]);
                }
        }
        short8 ah[2], al[2];
        #pragma unroll
        for (int mi = 0; mi < 2; ++mi) {
            S8U H, L;
            float xs[8] = {fa[2*mi].x, fa[2*mi].y, fa[2*mi].z, fa[2*mi].w,
                           fa[2*mi+1].x, fa[2*mi+1].y, fa[2*mi+1].z, fa[2*mi+1].w};
            #pragma unroll
            for (int j = 0; j < 8; ++j) split2(xs[j], H.u[j], L.u[j]);
            ah[mi] = H.v; al[mi] = L.v;
        }
        if (kt + 1 < KITER) {
            #pragma unroll
            for (int mi = 0; mi < 2; ++mi) {
                fa[2 * mi + 0] = *(const float4*)(arow[mi] + (kt + 1) * 32);
                fa[2 * mi + 1] = *(const float4*)(arow[mi] + (kt + 1) * 32 + 4);
            }
        }
        #pragma unroll
        for (int ni = 0; ni < 4; ++ni) {
            short8 bh = *(const short8*)&BS[buf][0][boff[ni]];
            short8 bl = *(const short8*)&BS[buf][1][boff[ni]];
            #pragma unroll
            for (int mi = 0; mi < 2; ++mi) {
                acc[mi][ni] = __builtin_amdgcn_mfma_f32_16x16x32_bf16(ah[mi], bh, acc[mi][ni], 0, 0, 0);
                acc[mi][ni] = __builtin_amdgcn_mfma_f32_16x16x32_bf16(ah[mi], bl, acc[mi][ni], 0, 0, 0);
                acc[mi][ni] = __builtin_amdgcn_mfma_f32_16x16x32_bf16(al[mi], bh, acc[mi][ni], 0, 0, 0);
            }
        }
        __syncthreads();
    }

    float* __restrict__ dst = blockIdx.z ? vtop : ktop;
    #pragma unroll
    for (int ni = 0; ni < 4; ++ni) {
        const int col = wn * 64 + ni * 16 + lrow;
        #pragma unroll
        for (int mi = 0; mi < 2; ++mi)
            #pragma unroll
            for (int r = 0; r < 4; ++r) {
                const int grow = m0 + wm * 32 + mi * 16 + lq * 4 + r;
                if (grow < NM)
                    atomicAdd(&dst[(size_t)grow * ND + col], acc[mi][ni][r]);
            }
    }
}

// ---------------------------------------------------------------------------
// Kernel 2: q_norms only (q is already fully accumulated via atomics).
// One wave per row.
// ---------------------------------------------------------------------------
__global__ __launch_bounds__(256) void qnorm_kernel(
    const float* __restrict__ q, float* __restrict__ qn)
{
    const int wv = (blockIdx.x * 256 + threadIdx.x) >> 6;
    const int lane = threadIdx.x & 63;
    const float* r1 = q + (size_t)wv * ND;
    float a = r1[lane];
    float b = r1[lane + 64];
    float s = a * a + b * b;
    #pragma unroll
    for (int off = 32; off > 0; off >>= 1) s += __shfl_xor(s, off);
    if (lane == 0) qn[wv] = sqrtf(s);
}

// ---------------------------------------------------------------------------
// Kernel 3: exact top-k by rank counting (jax.lax.top_k tie rules).
// ---------------------------------------------------------------------------
__global__ __launch_bounds__(256) void topk_kernel(
    const float* __restrict__ qn, int* __restrict__ topi, int* __restrict__ cnt)
{
    __shared__ int rs[4][64];
    const int b = blockIdx.y;
    const int is = threadIdx.x & 63;
    const int i = blockIdx.x * 64 + is;
    const int chunk = threadIdx.x >> 6;
    const float vi = qn[(size_t)b * NT + i];
    const float4* qv = (const float4*)(qn + (size_t)b * NT + chunk * 1024);
    int rank = 0;
    #pragma unroll 4
    for (int j4 = 0; j4 < 256; ++j4) {
        float4 v = qv[j4];
        int j = chunk * 1024 + j4 * 4;
        rank += (v.x > vi || (v.x == vi && (j + 0) < i)) ? 1 : 0;
        rank += (v.y > vi || (v.y == vi && (j + 1) < i)) ? 1 : 0;
        rank += (v.z > vi || (v.z == vi && (j + 2) < i)) ? 1 : 0;
        rank += (v.w > vi || (v.w == vi && (j + 3) < i)) ? 1 : 0;
    }
    rs[chunk][is] = rank;
    __syncthreads();
    if (threadIdx.x < 64) {
        int rk = rs[0][threadIdx.x] + rs[1][threadIdx.x] + rs[2][threadIdx.x] + rs[3][threadIdx.x];
        if (rk < NK) {
            int p = atomicAdd(&cnt[b], 1);
            topi[b * KPAD + p] = blockIdx.x * 64 + threadIdx.x;
        }
    }
}

// ---------------------------------------------------------------------------
// Kernel 5: per (batch, top-k row): scores -> softmax -> PV -> scatter.
// ---------------------------------------------------------------------------
__global__ __launch_bounds__(256) void attn_kernel(
    const float* __restrict__ q, const float* __restrict__ ktop,
    const float* __restrict__ vtop, const int* __restrict__ topi,
    float* __restrict__ out)
{
    __shared__ float qs[ND];
    __shared__ float ss[KPAD];
    __shared__ float red[256];
    __shared__ float pv[2][ND];
    const int bi = blockIdx.x;
    const int b = bi / NK, i = bi % NK;
    const int t = threadIdx.x;
    const int row = topi[b * KPAD + i];
    if (t < ND) qs[t] = q[((size_t)b * NT + row) * ND + t];
    __syncthreads();

    const float scale = 0.08838834764831844f;   // 1/sqrt(128)
    float mymax = -1e30f;
    #pragma unroll
    for (int rep = 0; rep < 2; ++rep) {
        int j = t + rep * 256;
        if (j < NK) {
            const float4* kr = (const float4*)(ktop + ((size_t)b * NK + j) * ND);
            const float4* q4 = (const float4*)qs;
            float s = 0.f;
            #pragma unroll
            for (int dd = 0; dd < 32; ++dd) {
                float4 a = q4[dd], kv = kr[dd];
                s += a.x * kv.x + a.y * kv.y + a.z * kv.z + a.w * kv.w;
            }
            s *= scale;
            ss[j] = s;
            mymax = fmaxf(mymax, s);
        }
    }
    red[t] = mymax;
    __syncthreads();
    for (int off = 128; off > 0; off >>= 1) {
        if (t < off) red[t] = fmaxf(red[t], red[t + off]);
        __syncthreads();
    }
    const float mx = red[0];
    __syncthreads();

    float mysum = 0.f;
    #pragma unroll
    for (int rep = 0; rep < 2; ++rep) {
        int j = t + rep * 256;
        if (j < NK) {
            float p = __expf(ss[j] - mx);
            ss[j] = p;
            mysum += p;
        }
    }
    red[t] = mysum;
    __syncthreads();
    for (int off = 128; off > 0; off >>= 1) {
        if (t < off) red[t] += red[t + off];
        __syncthreads();
    }
    const float inv = 1.f / red[0];

    const int col = t & (ND - 1), half = t >> 7;
    float o = 0.f;
    #pragma unroll 4
    for (int j = half; j < NK; j += 2)
        o = fmaf(ss[j], vtop[((size_t)b * NK + j) * ND + col], o);
    pv[half][col] = o;
    __syncthreads();
    if (t < ND)
        out[((size_t)b * NT + row) * ND + t] = (pv[0][t] + pv[1][t]) * inv;
}

// ---------------------------------------------------------------------------
extern "C" void kernel_launch(void* const* d_in, const int* in_sizes, int n_in,
                              void* d_out, int out_size, void* d_ws, size_t ws_size,
                              hipStream_t stream)
{
    const float* index = (const float*)d_in[0];
    const float* Wq = (const float*)d_in[1];
    const float* Wk = (const float*)d_in[2];
    const float* Wv = (const float*)d_in[3];
    float* out = (float*)d_out;

    // ws: 10,137,856 B proven footprint.
    char* ws = (char*)d_ws;
    float*  q1   = (float*)(ws);                       // 8,388,608
    float*  qn   = (float*)(ws + 8388608);             //    65,536
    int*    topi = (int*)  (ws + 8454144);             //     8,192
    int*    cnt  = (int*)  (ws + 8462336);             //       256
    ushort* Bqt  = (ushort*)(ws + 8462592);            // 1,048,576 (phase 1)
    float*  ktop = (float*)(ws + 8462592);             //   837,632 (phase 2)
    float*  vtop = (float*)(ws + 9300224);             //   837,632 (phase 2)

    // d_out scratch: Bkt/Bvt (phase B), then output.
    ushort* Bkt = (ushort*)d_out;                      // 1,048,576
    ushort* Bvt = (ushort*)((char*)d_out + 1048576);   // 1,048,576

    hipMemsetAsync(cnt, 0, NB * sizeof(int), stream);
    hipMemsetAsync(q1, 0, 8388608, stream);            // atomic split-K accum

    bconv_tiles<<<dim3(64), dim3(256), 0, stream>>>(Wq, Bqt);
    qgemm_v3<<<dim3(NB * NT / 128, QSPLIT), dim3(256), 0, stream>>>(index, Bqt, q1);
    qnorm_kernel<<<dim3(NB * NT / 4), dim3(256), 0, stream>>>(q1, qn);
    topk_kernel<<<dim3(NT / 64, NB), dim3(256), 0, stream>>>(qn, topi, cnt);
    bconv_tiles<<<dim3(64), dim3(256), 0, stream>>>(Wk, Bkt);
    bconv_tiles<<<dim3(64), dim3(256), 0, stream>>>(Wv, Bvt);
    hipMemsetAsync(ktop, 0, 2 * 837632, stream);   // zero ktop+vtop (atomic accum)
    kvgemm_v3<<<dim3((NM + 63) / 64, KVSPLIT, 2), dim3(256), 0, stream>>>(
        index, Bkt, Bvt, topi, ktop, vtop);
    hipMemsetAsync(d_out, 0, (size_t)out_size * sizeof(float), stream);
    attn_kernel<<<dim3(NM), dim3(256), 0, stream>>>(q1, ktop, vtop, topi, out);
}

// Round 2
// 370.339 us; speedup vs baseline: 1.4743x; 1.4743x over previous
//
#include <hip/hip_runtime.h>
#include <hip/hip_bf16.h>

// Problem constants (Head_24799141167224)
// Inputs fp32, output fp32 (compared at bf16 precision, 2% rel).
// ws cap: 10,137,856 B proven (R4 fault at 11.2 MB). d_out = scratch until attn.
// R10 lesson: bulk atomicAdd split-K accumulation = ~32 B HBM RMW per scalar
// (R1: 16.7M atomics -> 518 MB WRITE_SIZE, 266 us). Partial buffers only.
#define NB 4
#define NT 4096
#define NC 2048
#define ND 128
#define NK 409      // int(0.1 * 4096)
#define KPAD 416
#define NM (NB * NK)   // 1636

typedef __attribute__((ext_vector_type(8))) short short8;   // 8 bf16
typedef __attribute__((ext_vector_type(4))) float f32x4;

union S8U { short8 v; ushort u[8]; };

// RNE split: x = hi + lo (both bf16), |x - hi - lo| <= ~2^-18 |x|
__device__ __forceinline__ void split2(float x, ushort& h, ushort& l) {
    union { float f; unsigned u; } a; a.f = x;
    unsigned r = a.u + 0x7FFFu + ((a.u >> 16) & 1u);
    h = (ushort)(r >> 16);
    union { unsigned u; float f; } hb; hb.u = ((unsigned)h) << 16;
    float res = x - hb.f;
    union { float f; unsigned u; } b; b.f = res;
    unsigned r2 = b.u + 0x7FFFu + ((b.u >> 16) & 1u);
    l = (ushort)(r2 >> 16);
}

__device__ __forceinline__ uint4 pack8(const ushort* s) {
    uint4 v;
    v.x = (unsigned)s[0] | ((unsigned)s[1] << 16);
    v.y = (unsigned)s[2] | ((unsigned)s[3] << 16);
    v.z = (unsigned)s[4] | ((unsigned)s[5] << 16);
    v.w = (unsigned)s[6] | ((unsigned)s[7] << 16);
    return v;
}

// B tile-major slot (layout produced by bconv_tiles; swizzle kept from the
// LDS era — harmless for global loads, fragments stay 16B-contiguous and a
// wave's 64 fragment loads for one ni span one contiguous 1 KB chunk).
__device__ __forceinline__ int slotOf(int n, int lq) {
    return n * 4 + ((lq + (n >> 1)) & 3);
}

// ---------------------------------------------------------------------------
// Kernel 0: W [2048][128] fp32 -> Bt tile-major bf16 hi/lo:
// Bt[kt][part][slot][8 ushorts], kt=k/32, slot=slotOf(n,lq), elems k=lq*8+j.
// 1 MB per weight matrix. One block per kt.
// ---------------------------------------------------------------------------
__global__ __launch_bounds__(256) void bconv_tiles(
    const float* __restrict__ W, ushort* __restrict__ Bt)
{
    const int kt = blockIdx.x;       // 0..63
    const int t = threadIdx.x;
    const int n = t & 127;
    const int lq0 = (t >> 7) * 2;    // 0 or 2
    #pragma unroll
    for (int e = 0; e < 2; ++e) {
        int lq = lq0 + e;
        ushort h[8], l[8];
        #pragma unroll
        for (int j = 0; j < 8; ++j) {
            float x = W[(size_t)(kt * 32 + lq * 8 + j) * ND + n];  // coalesced
            split2(x, h[j], l[j]);
        }
        int slot = slotOf(n, lq);
        *(uint4*)&Bt[((size_t)(kt * 2 + 0) * 512 + slot) * 8] = pack8(h);
        *(uint4*)&Bt[((size_t)(kt * 2 + 1) * 512 + slot) * 8] = pack8(l);
    }
}

// ---------------------------------------------------------------------------
// Kernel 1: q = index @ Wq. R11: barrier-free. Each wave owns an independent
// 16-row x 128-col strip (mi=1, ni=8). B fragments are loaded DIRECTLY from
// the tile-major global buffer (L2-resident, 1 MB/K-half) into registers —
// no LDS, no __syncthreads, no vmcnt(0) drain (R0's diagnosed 90% stall at
// 1 block/CU). 2-deep register double-buffer on B + A prefetch: loads of
// step kt+1 issue before MFMAs of step kt. Tile M=64 (4 waves), split-K=2
// -> grid (256,2) = 512 blocks = 2 blocks/CU, 8 independent waves/CU.
// Partial sums to q1 (ws) / q2 (d_out) — NON-atomic (R1 lesson).
// ---------------------------------------------------------------------------
#define QSPLIT 2
__global__ __launch_bounds__(256) void qgemm_v5(
    const float* __restrict__ A, const ushort* __restrict__ Bt,
    float* __restrict__ q1, float* __restrict__ q2)
{
    const int tid = threadIdx.x;
    const int w = tid >> 6, lane = tid & 63;
    const int lrow = lane & 15, lq = lane >> 4;
    const int m0 = blockIdx.x * 64;
    const int KITER = (NC / QSPLIT) / 32;                 // 32
    const int kt0 = blockIdx.y * KITER;
    const int kb = blockIdx.y * (NC / QSPLIT);

    const float* arow = A + (size_t)(m0 + w * 16 + lrow) * NC + kb + lq * 8;

    int boff[8];
    #pragma unroll
    for (int ni = 0; ni < 8; ++ni)
        boff[ni] = slotOf(ni * 16 + lrow, lq) * 8;

    f32x4 acc[8];
    #pragma unroll
    for (int i = 0; i < 8; ++i) acc[i] = (f32x4){0.f, 0.f, 0.f, 0.f};

    // prologue: B(0) into set A, A(0) into fa
    short8 bhA[8], blA[8], bhB[8], blB[8];
    {
        const ushort* gb = Bt + (size_t)kt0 * 8192;   // 2*512*8 ushorts per kt
        #pragma unroll
        for (int ni = 0; ni < 8; ++ni) {
            bhA[ni] = *(const short8*)(gb + boff[ni]);
            blA[ni] = *(const short8*)(gb + 4096 + boff[ni]);
        }
    }
    float4 fa0 = *(const float4*)(arow + 0);
    float4 fa1 = *(const float4*)(arow + 4);

#define QSTEP(BHC, BLC, BHN, BLN, KT)                                         \
    {                                                                         \
        short8 ah, al;                                                        \
        {                                                                     \
            S8U H, L;                                                         \
            float xs[8] = {fa0.x, fa0.y, fa0.z, fa0.w,                        \
                           fa1.x, fa1.y, fa1.z, fa1.w};                       \
            _Pragma("unroll")                                                 \
            for (int j = 0; j < 8; ++j) split2(xs[j], H.u[j], L.u[j]);        \
            ah = H.v; al = L.v;                                               \
        }                                                                     \
        const int ktn = ((KT) + 1 < KITER) ? (KT) + 1 : (KT);                 \
        const ushort* gbn = Bt + (size_t)(kt0 + ktn) * 8192;                  \
        _Pragma("unroll")                                                     \
        for (int ni = 0; ni < 8; ++ni) {                                      \
            BHN[ni] = *(const short8*)(gbn + boff[ni]);                       \
            BLN[ni] = *(const short8*)(gbn + 4096 + boff[ni]);                \
        }                                                                     \
        fa0 = *(const float4*)(arow + ktn * 32);                              \
        fa1 = *(const float4*)(arow + ktn * 32 + 4);                          \
        _Pragma("unroll")                                                     \
        for (int ni = 0; ni < 8; ++ni) {                                      \
            acc[ni] = __builtin_amdgcn_mfma_f32_16x16x32_bf16(ah, BHC[ni], acc[ni], 0, 0, 0); \
            acc[ni] = __builtin_amdgcn_mfma_f32_16x16x32_bf16(ah, BLC[ni], acc[ni], 0, 0, 0); \
            acc[ni] = __builtin_amdgcn_mfma_f32_16x16x32_bf16(al, BHC[ni], acc[ni], 0, 0, 0); \
        }                                                                     \
    }

    for (int kt = 0; kt < KITER; kt += 2) {
        QSTEP(bhA, blA, bhB, blB, kt);
        QSTEP(bhB, blB, bhA, blA, kt + 1);
    }
#undef QSTEP

    float* __restrict__ qd = blockIdx.y ? q2 : q1;
    // C/D layout: col = lane&15 (lrow), row = lq*4 + r
    #pragma unroll
    for (int ni = 0; ni < 8; ++ni) {
        const int col = ni * 16 + lrow;
        #pragma unroll
        for (int r = 0; r < 4; ++r) {
            const int grow = m0 + w * 16 + lq * 4 + r;
            qd[(size_t)grow * ND + col] = acc[ni][r];
        }
    }
}

// ---------------------------------------------------------------------------
// Kernel 1b: gathered K/V projection, same barrier-free structure. Wave =
// 16 gathered rows x 128 cols. grid (26, KVSPLIT=8, 2) = 416 blocks; small
// atomic epilogue (3.3M atomics total ~ 100 MB RMW — acceptable at this
// scale, partial buffers don't fit ws).
// ---------------------------------------------------------------------------
#define KVSPLIT 8
__global__ __launch_bounds__(256) void kvgemm_v5(
    const float* __restrict__ X, const ushort* __restrict__ Bkt,
    const ushort* __restrict__ Bvt, const int* __restrict__ topi,
    float* __restrict__ ktop, float* __restrict__ vtop)
{
    const int tid = threadIdx.x;
    const int w = tid >> 6, lane = tid & 63;
    const int lrow = lane & 15, lq = lane >> 4;
    const int m0 = blockIdx.x * 64;
    const int KITER = (NC / KVSPLIT) / 32;                // 8
    const int kt0 = blockIdx.y * KITER;
    const int kb = blockIdx.y * (NC / KVSPLIT);
    const ushort* __restrict__ Bt = blockIdx.z ? Bvt : Bkt;

    const int gi = m0 + w * 16 + lrow;
    const int giC = gi < NM ? gi : NM - 1;
    const int b = giC / NK, ii = giC % NK;
    const int src = topi[b * KPAD + ii];
    const float* arow = X + ((size_t)b * NT + src) * NC + kb + lq * 8;

    int boff[8];
    #pragma unroll
    for (int ni = 0; ni < 8; ++ni)
        boff[ni] = slotOf(ni * 16 + lrow, lq) * 8;

    f32x4 acc[8];
    #pragma unroll
    for (int i = 0; i < 8; ++i) acc[i] = (f32x4){0.f, 0.f, 0.f, 0.f};

    short8 bhA[8], blA[8], bhB[8], blB[8];
    {
        const ushort* gb = Bt + (size_t)kt0 * 8192;
        #pragma unroll
        for (int ni = 0; ni < 8; ++ni) {
            bhA[ni] = *(const short8*)(gb + boff[ni]);
            blA[ni] = *(const short8*)(gb + 4096 + boff[ni]);
        }
    }
    float4 fa0 = *(const float4*)(arow + 0);
    float4 fa1 = *(const float4*)(arow + 4);

#define QSTEP(BHC, BLC, BHN, BLN, KT)                                         \
    {                                                                         \
        short8 ah, al;                                                        \
        {                                                                     \
            S8U H, L;                                                         \
            float xs[8] = {fa0.x, fa0.y, fa0.z, fa0.w,                        \
                           fa1.x, fa1.y, fa1.z, fa1.w};                       \
            _Pragma("unroll")                                                 \
            for (int j = 0; j < 8; ++j) split2(xs[j], H.u[j], L.u[j]);        \
            ah = H.v; al = L.v;                                               \
        }                                                                     \
        const int ktn = ((KT) + 1 < KITER) ? (KT) + 1 : (KT);                 \
        const ushort* gbn = Bt + (size_t)(kt0 + ktn) * 8192;                  \
        _Pragma("unroll")                                                     \
        for (int ni = 0; ni < 8; ++ni) {                                      \
            BHN[ni] = *(const short8*)(gbn + boff[ni]);                       \
            BLN[ni] = *(const short8*)(gbn + 4096 + boff[ni]);                \
        }                                                                     \
        fa0 = *(const float4*)(arow + ktn * 32);                              \
        fa1 = *(const float4*)(arow + ktn * 32 + 4);                          \
        _Pragma("unroll")                                                     \
        for (int ni = 0; ni < 8; ++ni) {                                      \
            acc[ni] = __builtin_amdgcn_mfma_f32_16x16x32_bf16(ah, BHC[ni], acc[ni], 0, 0, 0); \
            acc[ni] = __builtin_amdgcn_mfma_f32_16x16x32_bf16(ah, BLC[ni], acc[ni], 0, 0, 0); \
            acc[ni] = __builtin_amdgcn_mfma_f32_16x16x32_bf16(al, BHC[ni], acc[ni], 0, 0, 0); \
        }                                                                     \
    }

    for (int kt = 0; kt < KITER; kt += 2) {
        QSTEP(bhA, blA, bhB, blB, kt);
        QSTEP(bhB, blB, bhA, blA, kt + 1);
    }
#undef QSTEP

    float* __restrict__ dst = blockIdx.z ? vtop : ktop;
    #pragma unroll
    for (int ni = 0; ni < 8; ++ni) {
        const int col = ni * 16 + lrow;
        #pragma unroll
        for (int r = 0; r < 4; ++r) {
            const int grow = m0 + w * 16 + lq * 4 + r;
            if (grow < NM)
                atomicAdd(&dst[(size_t)grow * ND + col], acc[ni][r]);
        }
    }
}

// ---------------------------------------------------------------------------
// Kernel 2: q = q1 + q2 (in-place into q1) + q_norms. One wave per row.
// ---------------------------------------------------------------------------
__global__ __launch_bounds__(256) void qnorm_kernel(
    float* __restrict__ q1, const float* __restrict__ q2, float* __restrict__ qn)
{
    const int wv = (blockIdx.x * 256 + threadIdx.x) >> 6;
    const int lane = threadIdx.x & 63;
    float* r1 = q1 + (size_t)wv * ND;
    const float* r2 = q2 + (size_t)wv * ND;
    float a = r1[lane] + r2[lane];
    float b = r1[lane + 64] + r2[lane + 64];
    r1[lane] = a;
    r1[lane + 64] = b;
    float s = a * a + b * b;
    #pragma unroll
    for (int off = 32; off > 0; off >>= 1) s += __shfl_xor(s, off);
    if (lane == 0) qn[wv] = sqrtf(s);
}

// ---------------------------------------------------------------------------
// Kernel 3: exact top-k by rank counting (jax.lax.top_k tie rules).
// ---------------------------------------------------------------------------
__global__ __launch_bounds__(256) void topk_kernel(
    const float* __restrict__ qn, int* __restrict__ topi, int* __restrict__ cnt)
{
    __shared__ int rs[4][64];
    const int b = blockIdx.y;
    const int is = threadIdx.x & 63;
    const int i = blockIdx.x * 64 + is;
    const int chunk = threadIdx.x >> 6;
    const float vi = qn[(size_t)b * NT + i];
    const float4* qv = (const float4*)(qn + (size_t)b * NT + chunk * 1024);
    int rank = 0;
    #pragma unroll 4
    for (int j4 = 0; j4 < 256; ++j4) {
        float4 v = qv[j4];
        int j = chunk * 1024 + j4 * 4;
        rank += (v.x > vi || (v.x == vi && (j + 0) < i)) ? 1 : 0;
        rank += (v.y > vi || (v.y == vi && (j + 1) < i)) ? 1 : 0;
        rank += (v.z > vi || (v.z == vi && (j + 2) < i)) ? 1 : 0;
        rank += (v.w > vi || (v.w == vi && (j + 3) < i)) ? 1 : 0;
    }
    rs[chunk][is] = rank;
    __syncthreads();
    if (threadIdx.x < 64) {
        int rk = rs[0][threadIdx.x] + rs[1][threadIdx.x] + rs[2][threadIdx.x] + rs[3][threadIdx.x];
        if (rk < NK) {
            int p = atomicAdd(&cnt[b], 1);
            topi[b * KPAD + p] = blockIdx.x * 64 + threadIdx.x;
        }
    }
}

// ---------------------------------------------------------------------------
// Kernel 5: per (batch, top-k row): scores -> softmax -> PV -> scatter.
// ---------------------------------------------------------------------------
__global__ __launch_bounds__(256) void attn_kernel(
    const float* __restrict__ q, const float* __restrict__ ktop,
    const float* __restrict__ vtop, const int* __restrict__ topi,
    float* __restrict__ out)
{
    __shared__ float qs[ND];
    __shared__ float ss[KPAD];
    __shared__ float red[256];
    __shared__ float pv[2][ND];
    const int bi = blockIdx.x;
    const int b = bi / NK, i = bi % NK;
    const int t = threadIdx.x;
    const int row = topi[b * KPAD + i];
    if (t < ND) qs[t] = q[((size_t)b * NT + row) * ND + t];
    __syncthreads();

    const float scale = 0.08838834764831844f;   // 1/sqrt(128)
    float mymax = -1e30f;
    #pragma unroll
    for (int rep = 0; rep < 2; ++rep) {
        int j = t + rep * 256;
        if (j < NK) {
            const float4* kr = (const float4*)(ktop + ((size_t)b * NK + j) * ND);
            const float4* q4 = (const float4*)qs;
            float s = 0.f;
            #pragma unroll
            for (int dd = 0; dd < 32; ++dd) {
                float4 a = q4[dd], kv = kr[dd];
                s += a.x * kv.x + a.y * kv.y + a.z * kv.z + a.w * kv.w;
            }
            s *= scale;
            ss[j] = s;
            mymax = fmaxf(mymax, s);
        }
    }
    red[t] = mymax;
    __syncthreads();
    for (int off = 128; off > 0; off >>= 1) {
        if (t < off) red[t] = fmaxf(red[t], red[t + off]);
        __syncthreads();
    }
    const float mx = red[0];
    __syncthreads();

    float mysum = 0.f;
    #pragma unroll
    for (int rep = 0; rep < 2; ++rep) {
        int j = t + rep * 256;
        if (j < NK) {
            float p = __expf(ss[j] - mx);
            ss[j] = p;
            mysum += p;
        }
    }
    red[t] = mysum;
    __syncthreads();
    for (int off = 128; off > 0; off >>= 1) {
        if (t < off) red[t] += red[t + off];
        __syncthreads();
    }
    const float inv = 1.f / red[0];

    const int col = t & (ND - 1), half = t >> 7;
    float o = 0.f;
    #pragma unroll 4
    for (int j = half; j < NK; j += 2)
        o = fmaf(ss[j], vtop[((size_t)b * NK + j) * ND + col], o);
    pv[half][col] = o;
    __syncthreads();
    if (t < ND)
        out[((size_t)b * NT + row) * ND + t] = (pv[0][t] + pv[1][t]) * inv;
}

// ---------------------------------------------------------------------------
extern "C" void kernel_launch(void* const* d_in, const int* in_sizes, int n_in,
                              void* d_out, int out_size, void* d_ws, size_t ws_size,
                              hipStream_t stream)
{
    const float* index = (const float*)d_in[0];
    const float* Wq = (const float*)d_in[1];
    const float* Wk = (const float*)d_in[2];
    const float* Wv = (const float*)d_in[3];
    float* out = (float*)d_out;

    // ws: 10,137,856 B proven footprint.
    char* ws = (char*)d_ws;
    float*  q1   = (float*)(ws);                       // 8,388,608
    float*  qn   = (float*)(ws + 8388608);             //    65,536
    int*    topi = (int*)  (ws + 8454144);             //     8,192
    int*    cnt  = (int*)  (ws + 8462336);             //       256
    ushort* Bqt  = (ushort*)(ws + 8462592);            // 1,048,576 (phase 1)
    float*  ktop = (float*)(ws + 8462592);             //   837,632 (phase 2)
    float*  vtop = (float*)(ws + 9300224);             //   837,632 (phase 2)

    // d_out scratch: q2 partial (phase A), then Bkt/Bvt (phase B), then output.
    float*  q2  = (float*)d_out;
    ushort* Bkt = (ushort*)d_out;                      // 1,048,576
    ushort* Bvt = (ushort*)((char*)d_out + 1048576);   // 1,048,576

    hipMemsetAsync(cnt, 0, NB * sizeof(int), stream);

    bconv_tiles<<<dim3(64), dim3(256), 0, stream>>>(Wq, Bqt);
    qgemm_v5<<<dim3(NB * NT / 64, QSPLIT), dim3(256), 0, stream>>>(index, Bqt, q1, q2);
    qnorm_kernel<<<dim3(NB * NT / 4), dim3(256), 0, stream>>>(q1, q2, qn);
    topk_kernel<<<dim3(NT / 64, NB), dim3(256), 0, stream>>>(qn, topi, cnt);
    bconv_tiles<<<dim3(64), dim3(256), 0, stream>>>(Wk, Bkt);
    bconv_tiles<<<dim3(64), dim3(256), 0, stream>>>(Wv, Bvt);
    hipMemsetAsync(ktop, 0, 2 * 837632, stream);   // zero ktop+vtop (atomic accum)
    kvgemm_v5<<<dim3((NM + 63) / 64, KVSPLIT, 2), dim3(256), 0, stream>>>(
        index, Bkt, Bvt, topi, ktop, vtop);
    hipMemsetAsync(d_out, 0, (size_t)out_size * sizeof(float), stream);
    attn_kernel<<<dim3(NM), dim3(256), 0, stream>>>(q1, ktop, vtop, topi, out);
}